// Round 10
// baseline (166.325 us; speedup 1.0000x reference)
//
#include <hip/hip_runtime.h>
#include <hip/hip_bf16.h>

// AFT-Full: out = (exp(w) @ (exp(K)*V)) / (exp(w) @ exp(K)),  K,V = x@W+b
// B=8, T=2048, DIM=1024, HID=128. fp32 in/out; bf16 MFMA internally.
// R9: fatter tiles — BM=64, BN=256, 512 threads / 8 waves, wave tile 64x32
//     (num col h + den col h+128 per wave), counted-vmcnt dbuf kept.
//     Grid=256 (1 block/CU, 80KB LDS); gemm2 XCD-pinned per batch (b=bid&7).

#define T_    2048
#define DIM_  1024
#define HID_  128

typedef __attribute__((ext_vector_type(8))) __bf16 bf16x8;
typedef __attribute__((ext_vector_type(4))) float f32x4;
typedef __attribute__((ext_vector_type(4))) unsigned short us4;
typedef __attribute__((ext_vector_type(8))) unsigned short us8;

typedef const unsigned int __attribute__((address_space(1)))* gas_t;
typedef unsigned int __attribute__((address_space(3)))* las_t;

__device__ __forceinline__ unsigned short f2bf(float f) {
    unsigned int u = __builtin_bit_cast(unsigned int, f);
    u += 0x7fffu + ((u >> 16) & 1u);   // RNE
    return (unsigned short)(u >> 16);
}

__device__ __forceinline__ void gload16(const void* g, void* l) {
    __builtin_amdgcn_global_load_lds((gas_t)g, (las_t)l, 16, 0, 0);
}

// ---------------------------------------------------------------- prep_ew
__global__ __launch_bounds__(256) void prep_ew(const float* __restrict__ w,
                                               unsigned short* __restrict__ ew) {
    int idx = blockIdx.x * 256 + threadIdx.x;   // float4 index, 1M total
    f32x4 v = ((const f32x4*)w)[idx];
    us4 o;
    o[0] = f2bf(__expf(v[0]));
    o[1] = f2bf(__expf(v[1]));
    o[2] = f2bf(__expf(v[2]));
    o[3] = f2bf(__expf(v[3]));
    ((us4*)ew)[idx] = o;
}

// ---------------------------------------------------------------- prep_wkv
// wkvT[n][k]: n<128 -> wk_w[k][n], else wv_w[k][n-128]   (256 x 1024 bf16)
__global__ __launch_bounds__(256) void prep_wkv(const float* __restrict__ wk,
                                                const float* __restrict__ wv,
                                                unsigned short* __restrict__ wkvT) {
    int t = blockIdx.x * 256 + threadIdx.x;     // 32768 threads
    int n = t & 255, k0 = (t >> 8) << 3;
    const float* src = (n < 128) ? (wk + n) : (wv + (n - 128));
    us8 o;
#pragma unroll
    for (int j = 0; j < 8; j++) o[j] = f2bf(src[(size_t)(k0 + j) * 128]);
    *(us8*)(&wkvT[n * 1024 + k0]) = o;
}

// ---------------------------------------------------------------- gemm1
// K|V = x @ wkvT^T (+bias) for a 64-row tile; epilogue: eK=exp(K+bk),
// eKV=eK*(V+bv), transposed bf16 write into KVc[b]:
//   rows 0..127 = (eK*V)^T (num), rows 128..255 = (eK)^T (den)
// BM=64, BN=256, BK=64, 8 waves. Wave w: K col block [w*16,+16) (nf=0)
// paired with V col block [128+w*16,+16) (nf=1); acc[4][2].
// Counted-vmcnt dbuf: issue A(t+1)->regs(2) + B(t+1)->LDS(4); vmcnt(6);
// convert A(t)->As[cur] (swizzled ds_write); lgkmcnt(0); barrier; MFMA; barrier.
__global__ __launch_bounds__(512) void gemm1(const float* __restrict__ x,
                                             const unsigned short* __restrict__ wkvT,
                                             const float* __restrict__ wk_b,
                                             const float* __restrict__ wv_b,
                                             unsigned short* __restrict__ KVc) {
    __shared__ __align__(16) unsigned short As[2][64 * 64];    // linear+XOR swz (ds_write)
    __shared__ __align__(16) unsigned short Bs[2][256 * 64];   // linear (gload_lds, pre-swz src)
    const int tid  = threadIdx.x;
    const int m0   = blockIdx.x * 64;          // [0,16384)
    const int bb   = m0 >> 11;
    const int t0   = m0 & (T_ - 1);
    const int wave = tid >> 6, lane = tid & 63;
    const int lr = lane & 15, lq = lane >> 4;

    f32x4 acc[4][2];
#pragma unroll
    for (int i = 0; i < 4; i++)
#pragma unroll
        for (int j = 0; j < 2; j++) acc[i][j] = {0.f, 0.f, 0.f, 0.f};

    f32x4 aC[2], aN[2];
    // ---- prologue: issue tile-0 loads
#pragma unroll
    for (int i = 0; i < 2; i++) {
        int c = i * 512 + tid, r = c >> 4, c4 = (c & 15) * 4;
        aC[i] = *(const f32x4*)(x + (size_t)(m0 + r) * DIM_ + c4);
    }
#pragma unroll
    for (int i = 0; i < 4; i++) {
        int c = i * 512 + tid, r = c >> 3, kc = ((c & 7) ^ (r & 7)) * 8;
        gload16(wkvT + (size_t)r * DIM_ + kc, &Bs[0][(i * 512 + wave * 64) * 8]);
    }

    int cur = 0;
    for (int t = 0; t < 16; t++) {
        if (t < 15) {
            int k0 = (t + 1) * 64;
#pragma unroll
            for (int i = 0; i < 2; i++) {
                int c = i * 512 + tid, r = c >> 4, c4 = (c & 15) * 4;
                aN[i] = *(const f32x4*)(x + (size_t)(m0 + r) * DIM_ + k0 + c4);
            }
#pragma unroll
            for (int i = 0; i < 4; i++) {
                int c = i * 512 + tid, r = c >> 3, kc = ((c & 7) ^ (r & 7)) * 8;
                gload16(wkvT + (size_t)r * DIM_ + k0 + kc,
                        &Bs[cur ^ 1][(i * 512 + wave * 64) * 8]);
            }
            asm volatile("s_waitcnt vmcnt(6)" ::: "memory");   // tile t landed
        } else {
            asm volatile("s_waitcnt vmcnt(0)" ::: "memory");
        }
        // convert tile-t A regs -> As[cur], XOR-swizzled us4 writes
#pragma unroll
        for (int i = 0; i < 2; i++) {
            int c = i * 512 + tid, r = c >> 4, c4 = (c & 15) * 4;
            int sw = ((((c4 >> 3) ^ (r & 7)) << 3) | (c4 & 7));
            us4 o;
            o[0] = f2bf(aC[i][0]); o[1] = f2bf(aC[i][1]);
            o[2] = f2bf(aC[i][2]); o[3] = f2bf(aC[i][3]);
            *(us4*)(&As[cur][r * 64 + sw]) = o;
        }
        asm volatile("s_waitcnt lgkmcnt(0)" ::: "memory");
        __builtin_amdgcn_s_barrier();
#pragma unroll
        for (int ks = 0; ks < 64; ks += 32) {
            bf16x8 af[4], bfr[2];
#pragma unroll
            for (int mf = 0; mf < 4; mf++) {
                int ra = mf * 16 + lr;
                af[mf] = *(const bf16x8*)(&As[cur][ra * 64 + ((ks + lq * 8) ^ ((ra & 7) << 3))]);
            }
#pragma unroll
            for (int nf = 0; nf < 2; nf++) {
                int rb = nf * 128 + wave * 16 + lr;
                bfr[nf] = *(const bf16x8*)(&Bs[cur][rb * 64 + ((ks + lq * 8) ^ ((rb & 7) << 3))]);
            }
#pragma unroll
            for (int mf = 0; mf < 4; mf++)
#pragma unroll
                for (int nf = 0; nf < 2; nf++)
                    acc[mf][nf] = __builtin_amdgcn_mfma_f32_16x16x32_bf16(
                        af[mf], bfr[nf], acc[mf][nf], 0, 0, 0);
        }
        __builtin_amdgcn_s_barrier();
        aC[0] = aN[0]; aC[1] = aN[1];
        cur ^= 1;
    }

    // ---- epilogue: eK/eKV + transpose via LDS (overlay on Bs), bf16 write
    unsigned short* ekvS = &Bs[0][0];          // [128][72]
    unsigned short* ekS  = ekvS + 128 * 72;    // [128][72]
    {
        int h = wave * 16 + lr;                // [0,128)
        float bk = wk_b[h], bv = wv_b[h];
#pragma unroll
        for (int mf = 0; mf < 4; mf++) {
            int m = mf * 16 + lq * 4;          // [0,64)
            us4 ok, okv;
#pragma unroll
            for (int j = 0; j < 4; j++) {
                float ek = __expf(acc[mf][0][j] + bk);
                float vv = acc[mf][1][j] + bv;
                ok[j]  = f2bf(ek);
                okv[j] = f2bf(ek * vv);
            }
            *(us4*)(ekS  + h * 72 + m) = ok;
            *(us4*)(ekvS + h * 72 + m) = okv;
        }
    }
    __syncthreads();
    unsigned short* dst = KVc + (size_t)bb * 256 * T_;
#pragma unroll
    for (int i = 0; i < 2; i++) {
        int c = i * 512 + tid;                 // 1024 us8 chunks per array
        int h = c >> 3, mc = (c & 7) * 8;
        us8 vkv = *(const us8*)(ekvS + h * 72 + mc);
        us8 vk  = *(const us8*)(ekS  + h * 72 + mc);
        *(us8*)(dst + (size_t)h * T_ + t0 + mc)         = vkv;   // num rows
        *(us8*)(dst + (size_t)(128 + h) * T_ + t0 + mc) = vk;    // den rows
    }
}

// ---------------------------------------------------------------- gemm2
// out[b][t][h] = (ew[t,:] @ eKV^T[h,:]) / (ew[t,:] @ eK^T[h,:])
// BM=64 (t), BN=256 (128 num + 128 den), BK=64, K=2048, 8 waves.
// Wave w: num col block [w*16,+16) (nf=0) + den block [128+w*16,+16) (nf=1);
// divide register-local. Grid 256, b = bid&7 (XCD-pinned KVc panel).
__global__ __launch_bounds__(512) void gemm2(const unsigned short* __restrict__ ew,
                                             const unsigned short* __restrict__ KVc,
                                             float* __restrict__ out) {
    __shared__ __align__(16) unsigned short As[2][64 * 64];
    __shared__ __align__(16) unsigned short Bs[2][256 * 64];
    const int tid  = threadIdx.x;
    const int bid  = blockIdx.x;
    const int b    = bid & 7;
    const int t0   = (bid >> 3) * 64;
    const unsigned short* Bsrc = KVc + (size_t)b * 256 * T_;
    const int wave = tid >> 6, lane = tid & 63;
    const int lr = lane & 15, lq = lane >> 4;

    f32x4 acc[4][2];
#pragma unroll
    for (int i = 0; i < 4; i++)
#pragma unroll
        for (int j = 0; j < 2; j++) acc[i][j] = {0.f, 0.f, 0.f, 0.f};

#define STAGE2(BUF, K0) do {                                                      \
    { int c = tid, r = c >> 3, kc = ((c & 7) ^ (r & 7)) * 8;                      \
      gload16(ew + (size_t)(t0 + r) * T_ + (K0) + kc,                             \
              &As[BUF][(wave * 64) * 8]); }                                       \
    _Pragma("unroll")                                                             \
    for (int i = 0; i < 4; i++) {                                                 \
        int c = i * 512 + tid, r = c >> 3, kc = ((c & 7) ^ (r & 7)) * 8;          \
        gload16(Bsrc + (size_t)r * T_ + (K0) + kc,                                \
                &Bs[BUF][(i * 512 + wave * 64) * 8]);                             \
    } } while (0)

    // ---- prologue: issue tile-0 loads
    STAGE2(0, 0);

    int cur = 0;
    for (int t = 0; t < 32; t++) {
        if (t < 31) {
            STAGE2(cur ^ 1, (t + 1) * 64);
            asm volatile("s_waitcnt vmcnt(5)" ::: "memory");   // tile t landed
        } else {
            asm volatile("s_waitcnt vmcnt(0)" ::: "memory");
        }
        __builtin_amdgcn_s_barrier();
#pragma unroll
        for (int ks = 0; ks < 64; ks += 32) {
            bf16x8 af[4], bfr[2];
#pragma unroll
            for (int mf = 0; mf < 4; mf++) {
                int ra = mf * 16 + lr;
                af[mf] = *(const bf16x8*)(&As[cur][ra * 64 + ((ks + lq * 8) ^ ((ra & 7) << 3))]);
            }
#pragma unroll
            for (int nf = 0; nf < 2; nf++) {
                int rb = nf * 128 + wave * 16 + lr;
                bfr[nf] = *(const bf16x8*)(&Bs[cur][rb * 64 + ((ks + lq * 8) ^ ((rb & 7) << 3))]);
            }
#pragma unroll
            for (int mf = 0; mf < 4; mf++)
#pragma unroll
                for (int nf = 0; nf < 2; nf++)
                    acc[mf][nf] = __builtin_amdgcn_mfma_f32_16x16x32_bf16(
                        af[mf], bfr[nf], acc[mf][nf], 0, 0, 0);
        }
        __builtin_amdgcn_s_barrier();
        cur ^= 1;
    }
#undef STAGE2

    // ---- epilogue: register-local divide, fp32 store
    float* ob = out + ((size_t)b * T_ + t0) * HID_;
    {
        int h = wave * 16 + lr;
#pragma unroll
        for (int mf = 0; mf < 4; mf++) {
            int m = mf * 16 + lq * 4;
#pragma unroll
            for (int j = 0; j < 4; j++)
                ob[(size_t)(m + j) * HID_ + h] = acc[mf][0][j] / acc[mf][1][j];
        }
    }
}

// ---------------------------------------------------------------- launch
extern "C" void kernel_launch(void* const* d_in, const int* in_sizes, int n_in,
                              void* d_out, int out_size, void* d_ws, size_t ws_size,
                              hipStream_t stream) {
    const float* x    = (const float*)d_in[0];
    const float* wk_w = (const float*)d_in[1];
    const float* wk_b = (const float*)d_in[2];
    const float* wv_w = (const float*)d_in[3];
    const float* wv_b = (const float*)d_in[4];
    const float* w    = (const float*)d_in[5];

    char* ws = (char*)d_ws;
    unsigned short* ws_ew   = (unsigned short*)(ws);                 // 8 MiB [2048][2048]
    unsigned short* ws_wkvT = (unsigned short*)(ws + (8u << 20));    // 0.5 MiB [256][1024]
    unsigned short* ws_KVc  = (unsigned short*)(ws + (9u << 20));    // 8 MiB [8][256][2048]

    prep_ew  <<<4096, 256, 0, stream>>>(w, ws_ew);
    prep_wkv <<<128,  256, 0, stream>>>(wk_w, wv_w, ws_wkvT);
    gemm1    <<<256,  512, 0, stream>>>(x, ws_wkvT, wk_b, wv_b, ws_KVc);
    gemm2    <<<256,  512, 0, stream>>>(ws_ew, ws_KVc, (float*)d_out);
}

// Round 11
// 165.945 us; speedup vs baseline: 1.0023x; 1.0023x over previous
//
#include <hip/hip_runtime.h>
#include <hip/hip_bf16.h>

// AFT-Full: out = (exp(w) @ (exp(K)*V)) / (exp(w) @ exp(K)),  K,V = x@W+b
// B=8, T=2048, DIM=1024, HID=128. fp32 in/out; bf16 MFMA internally.
// R11: 2-deep prefetch, 3 LDS buffers (120KB) — stages t+1,t+2 in flight
//      across barriers (vmcnt 2*ops), covering L2/HBM latency fully.

#define T_    2048
#define DIM_  1024
#define HID_  128

typedef __attribute__((ext_vector_type(8))) __bf16 bf16x8;
typedef __attribute__((ext_vector_type(4))) float f32x4;
typedef __attribute__((ext_vector_type(4))) unsigned short us4;
typedef __attribute__((ext_vector_type(8))) unsigned short us8;

typedef const unsigned int __attribute__((address_space(1)))* gas_t;
typedef unsigned int __attribute__((address_space(3)))* las_t;

__device__ __forceinline__ unsigned short f2bf(float f) {
    unsigned int u = __builtin_bit_cast(unsigned int, f);
    u += 0x7fffu + ((u >> 16) & 1u);   // RNE
    return (unsigned short)(u >> 16);
}

__device__ __forceinline__ void gload16(const void* g, void* l) {
    __builtin_amdgcn_global_load_lds((gas_t)g, (las_t)l, 16, 0, 0);
}

// ---------------------------------------------------------------- prep_ew
__global__ __launch_bounds__(256) void prep_ew(const float* __restrict__ w,
                                               unsigned short* __restrict__ ew) {
    int idx = blockIdx.x * 256 + threadIdx.x;   // float4 index, 1M total
    f32x4 v = ((const f32x4*)w)[idx];
    us4 o;
    o[0] = f2bf(__expf(v[0]));
    o[1] = f2bf(__expf(v[1]));
    o[2] = f2bf(__expf(v[2]));
    o[3] = f2bf(__expf(v[3]));
    ((us4*)ew)[idx] = o;
}

// ---------------------------------------------------------------- prep_wkv
// wkvT[n][k]: n<128 -> wk_w[k][n], else wv_w[k][n-128]   (256 x 1024 bf16)
__global__ __launch_bounds__(256) void prep_wkv(const float* __restrict__ wk,
                                                const float* __restrict__ wv,
                                                unsigned short* __restrict__ wkvT) {
    int t = blockIdx.x * 256 + threadIdx.x;     // 32768 threads
    int n = t & 255, k0 = (t >> 8) << 3;
    const float* src = (n < 128) ? (wk + n) : (wv + (n - 128));
    us8 o;
#pragma unroll
    for (int j = 0; j < 8; j++) o[j] = f2bf(src[(size_t)(k0 + j) * 128]);
    *(us8*)(&wkvT[n * 1024 + k0]) = o;
}

// ---------------------------------------------------------------- gemm1
// K|V = x @ wkvT^T (+bias) for a 64-row tile; epilogue: eK=exp(K+bk),
// eKV=eK*(V+bv), transposed bf16 write into KVc[b]:
//   rows 0..127 = (eK*V)^T (num), rows 128..255 = (eK)^T (den)
// BM=64, BN=256, BK=64, 8 waves, wave tile 64x32 (K col blk + paired V blk).
// 2-deep prefetch: per iter issue A(t+2)->regs(2) + B(t+2)->LDS(4);
// vmcnt(12) => tile-t landed, t+1/t+2 in flight; convert A(t)->As[t%3];
// lgkmcnt(0); barrier; MFMA; barrier.
__global__ __launch_bounds__(512) void gemm1(const float* __restrict__ x,
                                             const unsigned short* __restrict__ wkvT,
                                             const float* __restrict__ wk_b,
                                             const float* __restrict__ wv_b,
                                             unsigned short* __restrict__ KVc) {
    __shared__ __align__(16) unsigned short As[3][64 * 64];    // XOR-swz ds_write
    __shared__ __align__(16) unsigned short Bs[3][256 * 64];   // linear (gload_lds, pre-swz src)
    const int tid  = threadIdx.x;
    const int m0   = blockIdx.x * 64;          // [0,16384)
    const int bb   = m0 >> 11;
    const int t0   = m0 & (T_ - 1);
    const int wave = tid >> 6, lane = tid & 63;
    const int lr = lane & 15, lq = lane >> 4;

    f32x4 acc[4][2];
#pragma unroll
    for (int i = 0; i < 4; i++)
#pragma unroll
        for (int j = 0; j < 2; j++) acc[i][j] = {0.f, 0.f, 0.f, 0.f};

    f32x4 aT[2], aT1[2], aT2[2];

#define G1_LOADA(DST, K0) do {                                                    \
    _Pragma("unroll")                                                             \
    for (int i = 0; i < 2; i++) {                                                 \
        int c = i * 512 + tid, r = c >> 4, c4 = (c & 15) * 4;                     \
        DST[i] = *(const f32x4*)(x + (size_t)(m0 + r) * DIM_ + (K0) + c4);        \
    } } while (0)
#define G1_LOADB(BUF, K0) do {                                                    \
    _Pragma("unroll")                                                             \
    for (int i = 0; i < 4; i++) {                                                 \
        int c = i * 512 + tid, r = c >> 3, kc = ((c & 7) ^ (r & 7)) * 8;          \
        gload16(wkvT + (size_t)r * DIM_ + (K0) + kc,                              \
                &Bs[BUF][(i * 512 + wave * 64) * 8]);                             \
    } } while (0)

    // ---- prologue: issue tiles 0 and 1
    G1_LOADA(aT, 0);
    G1_LOADB(0, 0);
    G1_LOADA(aT1, 64);
    G1_LOADB(1, 64);

    for (int t = 0; t < 16; t++) {
        int cur = t % 3;
        if (t < 14) {
            G1_LOADA(aT2, (t + 2) * 64);
            G1_LOADB((t + 2) % 3, (t + 2) * 64);
            asm volatile("s_waitcnt vmcnt(12)" ::: "memory");  // tile t landed
        } else if (t < 15) {
            asm volatile("s_waitcnt vmcnt(6)" ::: "memory");
        } else {
            asm volatile("s_waitcnt vmcnt(0)" ::: "memory");
        }
        // convert tile-t A regs -> As[cur], XOR-swizzled us4 writes
#pragma unroll
        for (int i = 0; i < 2; i++) {
            int c = i * 512 + tid, r = c >> 4, c4 = (c & 15) * 4;
            int sw = ((((c4 >> 3) ^ (r & 7)) << 3) | (c4 & 7));
            us4 o;
            o[0] = f2bf(aT[i][0]); o[1] = f2bf(aT[i][1]);
            o[2] = f2bf(aT[i][2]); o[3] = f2bf(aT[i][3]);
            *(us4*)(&As[cur][r * 64 + sw]) = o;
        }
        asm volatile("s_waitcnt lgkmcnt(0)" ::: "memory");
        __builtin_amdgcn_s_barrier();
#pragma unroll
        for (int ks = 0; ks < 64; ks += 32) {
            bf16x8 af[4], bfr[2];
#pragma unroll
            for (int mf = 0; mf < 4; mf++) {
                int ra = mf * 16 + lr;
                af[mf] = *(const bf16x8*)(&As[cur][ra * 64 + ((ks + lq * 8) ^ ((ra & 7) << 3))]);
            }
#pragma unroll
            for (int nf = 0; nf < 2; nf++) {
                int rb = nf * 128 + wave * 16 + lr;
                bfr[nf] = *(const bf16x8*)(&Bs[cur][rb * 64 + ((ks + lq * 8) ^ ((rb & 7) << 3))]);
            }
#pragma unroll
            for (int mf = 0; mf < 4; mf++)
#pragma unroll
                for (int nf = 0; nf < 2; nf++)
                    acc[mf][nf] = __builtin_amdgcn_mfma_f32_16x16x32_bf16(
                        af[mf], bfr[nf], acc[mf][nf], 0, 0, 0);
        }
        __builtin_amdgcn_s_barrier();
        aT[0] = aT1[0]; aT[1] = aT1[1];
        aT1[0] = aT2[0]; aT1[1] = aT2[1];
    }
#undef G1_LOADA
#undef G1_LOADB

    // ---- epilogue: eK/eKV + transpose via LDS (overlay on Bs), bf16 write
    unsigned short* ekvS = &Bs[0][0];          // [128][72]
    unsigned short* ekS  = ekvS + 128 * 72;    // [128][72]
    {
        int h = wave * 16 + lr;                // [0,128)
        float bk = wk_b[h], bv = wv_b[h];
#pragma unroll
        for (int mf = 0; mf < 4; mf++) {
            int m = mf * 16 + lq * 4;          // [0,64)
            us4 ok, okv;
#pragma unroll
            for (int j = 0; j < 4; j++) {
                float ek = __expf(acc[mf][0][j] + bk);
                float vv = acc[mf][1][j] + bv;
                ok[j]  = f2bf(ek);
                okv[j] = f2bf(ek * vv);
            }
            *(us4*)(ekS  + h * 72 + m) = ok;
            *(us4*)(ekvS + h * 72 + m) = okv;
        }
    }
    __syncthreads();
    unsigned short* dst = KVc + (size_t)bb * 256 * T_;
#pragma unroll
    for (int i = 0; i < 2; i++) {
        int c = i * 512 + tid;                 // 1024 us8 chunks per array
        int h = c >> 3, mc = (c & 7) * 8;
        us8 vkv = *(const us8*)(ekvS + h * 72 + mc);
        us8 vk  = *(const us8*)(ekS  + h * 72 + mc);
        *(us8*)(dst + (size_t)h * T_ + t0 + mc)         = vkv;   // num rows
        *(us8*)(dst + (size_t)(128 + h) * T_ + t0 + mc) = vk;    // den rows
    }
}

// ---------------------------------------------------------------- gemm2
// out[b][t][h] = (ew[t,:] @ eKV^T[h,:]) / (ew[t,:] @ eK^T[h,:])
// BM=64 (t), BN=256 (128 num + 128 den), BK=64, K=2048, 8 waves.
// 2-deep prefetch, 3 buffers: issue STAGE(t+2); vmcnt(10); barrier;
// MFMA(t); barrier. Grid 256, b=bid&7 (XCD-pinned KVc panel).
__global__ __launch_bounds__(512) void gemm2(const unsigned short* __restrict__ ew,
                                             const unsigned short* __restrict__ KVc,
                                             float* __restrict__ out) {
    __shared__ __align__(16) unsigned short As[3][64 * 64];
    __shared__ __align__(16) unsigned short Bs[3][256 * 64];
    const int tid  = threadIdx.x;
    const int bid  = blockIdx.x;
    const int b    = bid & 7;
    const int t0   = (bid >> 3) * 64;
    const unsigned short* Bsrc = KVc + (size_t)b * 256 * T_;
    const int wave = tid >> 6, lane = tid & 63;
    const int lr = lane & 15, lq = lane >> 4;

    f32x4 acc[4][2];
#pragma unroll
    for (int i = 0; i < 4; i++)
#pragma unroll
        for (int j = 0; j < 2; j++) acc[i][j] = {0.f, 0.f, 0.f, 0.f};

#define STAGE2(BUF, K0) do {                                                      \
    { int c = tid, r = c >> 3, kc = ((c & 7) ^ (r & 7)) * 8;                      \
      gload16(ew + (size_t)(t0 + r) * T_ + (K0) + kc,                             \
              &As[BUF][(wave * 64) * 8]); }                                       \
    _Pragma("unroll")                                                             \
    for (int i = 0; i < 4; i++) {                                                 \
        int c = i * 512 + tid, r = c >> 3, kc = ((c & 7) ^ (r & 7)) * 8;          \
        gload16(Bsrc + (size_t)r * T_ + (K0) + kc,                                \
                &Bs[BUF][(i * 512 + wave * 64) * 8]);                             \
    } } while (0)

    // ---- prologue: issue tiles 0 and 1
    STAGE2(0, 0);
    STAGE2(1, 64);

    for (int t = 0; t < 32; t++) {
        int cur = t % 3;
        if (t < 30) {
            STAGE2((t + 2) % 3, (t + 2) * 64);
            asm volatile("s_waitcnt vmcnt(10)" ::: "memory");  // tile t landed
        } else if (t < 31) {
            asm volatile("s_waitcnt vmcnt(5)" ::: "memory");
        } else {
            asm volatile("s_waitcnt vmcnt(0)" ::: "memory");
        }
        __builtin_amdgcn_s_barrier();
#pragma unroll
        for (int ks = 0; ks < 64; ks += 32) {
            bf16x8 af[4], bfr[2];
#pragma unroll
            for (int mf = 0; mf < 4; mf++) {
                int ra = mf * 16 + lr;
                af[mf] = *(const bf16x8*)(&As[cur][ra * 64 + ((ks + lq * 8) ^ ((ra & 7) << 3))]);
            }
#pragma unroll
            for (int nf = 0; nf < 2; nf++) {
                int rb = nf * 128 + wave * 16 + lr;
                bfr[nf] = *(const bf16x8*)(&Bs[cur][rb * 64 + ((ks + lq * 8) ^ ((rb & 7) << 3))]);
            }
#pragma unroll
            for (int mf = 0; mf < 4; mf++)
#pragma unroll
                for (int nf = 0; nf < 2; nf++)
                    acc[mf][nf] = __builtin_amdgcn_mfma_f32_16x16x32_bf16(
                        af[mf], bfr[nf], acc[mf][nf], 0, 0, 0);
        }
        __builtin_amdgcn_s_barrier();
    }
#undef STAGE2

    // ---- epilogue: register-local divide, fp32 store
    float* ob = out + ((size_t)b * T_ + t0) * HID_;
    {
        int h = wave * 16 + lr;
#pragma unroll
        for (int mf = 0; mf < 4; mf++) {
            int m = mf * 16 + lq * 4;
#pragma unroll
            for (int j = 0; j < 4; j++)
                ob[(size_t)(m + j) * HID_ + h] = acc[mf][0][j] / acc[mf][1][j];
        }
    }
}

// ---------------------------------------------------------------- launch
extern "C" void kernel_launch(void* const* d_in, const int* in_sizes, int n_in,
                              void* d_out, int out_size, void* d_ws, size_t ws_size,
                              hipStream_t stream) {
    const float* x    = (const float*)d_in[0];
    const float* wk_w = (const float*)d_in[1];
    const float* wk_b = (const float*)d_in[2];
    const float* wv_w = (const float*)d_in[3];
    const float* wv_b = (const float*)d_in[4];
    const float* w    = (const float*)d_in[5];

    char* ws = (char*)d_ws;
    unsigned short* ws_ew   = (unsigned short*)(ws);                 // 8 MiB [2048][2048]
    unsigned short* ws_wkvT = (unsigned short*)(ws + (8u << 20));    // 0.5 MiB [256][1024]
    unsigned short* ws_KVc  = (unsigned short*)(ws + (9u << 20));    // 8 MiB [8][256][2048]

    prep_ew  <<<4096, 256, 0, stream>>>(w, ws_ew);
    prep_wkv <<<128,  256, 0, stream>>>(wk_w, wv_w, ws_wkvT);
    gemm1    <<<256,  512, 0, stream>>>(x, ws_wkvT, wk_b, wv_b, ws_KVc);
    gemm2    <<<256,  512, 0, stream>>>(ws_ew, ws_KVc, (float*)d_out);
}